// Round 10
// baseline (67.779 us; speedup 1.0000x reference)
//
#include <hip/hip_runtime.h>

#define BB 32
#define SS 512
#define FF 256
#define NN 8
#define L 16               // chunk length
#define NCH 32             // SS/L
#define CGF 8              // channels per block
#define NTF 256            // threads per block
#define XST 9              // xs base row stride (words)
#define VST 68             // vs row stride (words)

typedef float f32x4 __attribute__((ext_vector_type(4)));

// chunk-skewed xs index: breaks the j-group 4-way bank conflict (-> <=2-way)
__device__ __forceinline__ int xsidx(int t, int c) {
    return t * XST + (t >> 4) + c;
}

__global__ __launch_bounds__(NTF) void hippo_fused3(
    const float* __restrict__ x,
    const float* __restrict__ Ad,
    const float* __restrict__ Bd,
    float* __restrict__ out)
{
    __shared__ __align__(16) float xs[SS * XST + NCH + 8];
    __shared__ __align__(16) float vs[NCH * VST];
    __shared__ __align__(16) float pw[5][64];         // P^(2^k), P = M^16
    __shared__ __align__(16) float Mp[4][64];         // M^1,2,4,8
    __shared__ __align__(16) float Ks[L][NN];         // K[i] = M^(15-i) B

    const int tid = threadIdx.x;

    // XCD-chunked swizzle
    const int h  = blockIdx.x;
    const int g  = (h & 7) * 128 + (h >> 3);
    const int b  = g >> 5;
    const int f0 = (g & 31) * CGF;

    // ---- wave 0: matrix algebra  ||  waves 1-3: stage x tile ----
    if (tid < 64) {
        const int m = tid >> 3, n = tid & 7;
        Mp[0][tid] = Ad[n * NN + m];                 // M = A^T
#pragma unroll
        for (int s = 1; s < 4; ++s) {                // M^2, M^4, M^8
            float a = 0.f;
#pragma unroll
            for (int t = 0; t < 8; ++t) a = fmaf(Mp[s-1][m*8+t], Mp[s-1][t*8+n], a);
            Mp[s][tid] = a;
        }
        {   float a = 0.f;                           // M^16
#pragma unroll
            for (int t = 0; t < 8; ++t) a = fmaf(Mp[3][m*8+t], Mp[3][t*8+n], a);
            pw[0][tid] = a; }
#pragma unroll
        for (int k = 1; k < 5; ++k) {                // M^32..M^256
            float a = 0.f;
#pragma unroll
            for (int t = 0; t < 8; ++t) a = fmaf(pw[k-1][m*8+t], pw[k-1][t*8+n], a);
            pw[k][tid] = a;
        }
        if (tid < L) {                               // K[i] = M^(15-i) B
            const int e = 15 - tid;
            float v[8];
#pragma unroll
            for (int q = 0; q < 8; ++q) v[q] = Bd[q];
#pragma unroll
            for (int s = 0; s < 4; ++s) {
                if (e & (1 << s)) {
                    float nv[8];
#pragma unroll
                    for (int r = 0; r < 8; ++r) {
                        float a = 0.f;
#pragma unroll
                        for (int c2 = 0; c2 < 8; ++c2)
                            a = fmaf(Mp[s][r * 8 + c2], v[c2], a);
                        nv[r] = a;
                    }
#pragma unroll
                    for (int r = 0; r < 8; ++r) v[r] = nv[r];
                }
            }
#pragma unroll
            for (int r = 0; r < 8; ++r) Ks[tid][r] = v[r];
        }
    } else {
        const float* xb = x + (size_t)b * SS * FF + f0;
#pragma unroll
        for (int k = 0; k < 6; ++k) {
            const int i2 = (tid - 64) + k * 192;     // 0..1151, need 0..1023
            if (i2 < 1024) {
                const int t = i2 >> 1, q = i2 & 1;
                float4 v = *(const float4*)(xb + (size_t)t * FF + q * 4);
                float* d = &xs[xsidx(t, q * 4)];
                d[0] = v.x; d[1] = v.y; d[2] = v.z; d[3] = v.w;
            }
        }
    }

    // thread-uniform A/B -> scalar regs (for emit)
    float As[NN * NN];
#pragma unroll
    for (int i = 0; i < NN * NN; ++i) As[i] = Ad[i];
    float Bv[NN];
#pragma unroll
    for (int m = 0; m < NN; ++m) Bv[m] = Bd[m];

    __syncthreads();   // barrier 1: xs + algebra ready

    // ---- phase 1: chunk-end state from zero via Krylov sum ----
    const int j  = tid >> 3;            // chunk 0..31
    const int ch = tid & 7;             // channel-in-block
    const int t0 = j * L;
    {
        float c[NN];
#pragma unroll
        for (int m = 0; m < NN; ++m) c[m] = 0.f;
#pragma unroll
        for (int i = 0; i < L; ++i) {
            const float xt = xs[xsidx(t0 + i, ch)];
            const float4 k0 = *(const float4*)&Ks[i][0];
            const float4 k1 = *(const float4*)&Ks[i][4];
            c[0] = fmaf(k0.x, xt, c[0]); c[1] = fmaf(k0.y, xt, c[1]);
            c[2] = fmaf(k0.z, xt, c[2]); c[3] = fmaf(k0.w, xt, c[3]);
            c[4] = fmaf(k1.x, xt, c[4]); c[5] = fmaf(k1.y, xt, c[5]);
            c[6] = fmaf(k1.z, xt, c[6]); c[7] = fmaf(k1.w, xt, c[7]);
        }
        float* vj = &vs[j * VST + ch * NN];
        *(float4*)(vj)     = make_float4(c[0], c[1], c[2], c[3]);
        *(float4*)(vj + 4) = make_float4(c[4], c[5], c[6], c[7]);
    }
    __syncthreads();   // barrier 2: chunk-end states in vs

    // ---- phase 2: in-wave shfl Hillis-Steele (no barriers) ----
    {
        const int lane = tid & 63;
        const int w    = tid >> 6;
        const int js   = lane >> 1;
        const int cs   = 2 * w + (lane & 1);

        float s[NN];
        {
            const float* vp = &vs[js * VST + cs * NN];
            float4 p0 = *(const float4*)(vp);
            float4 p1 = *(const float4*)(vp + 4);
            s[0] = p0.x; s[1] = p0.y; s[2] = p0.z; s[3] = p0.w;
            s[4] = p1.x; s[5] = p1.y; s[6] = p1.z; s[7] = p1.w;
        }
#pragma unroll
        for (int k = 0; k < 5; ++k) {
            const int d = 1 << k;
            float prev[NN];
#pragma unroll
            for (int m = 0; m < NN; ++m) prev[m] = __shfl_up(s[m], 2 * d, 64);
            if (js >= d) {
#pragma unroll
                for (int m = 0; m < NN; ++m) {
                    const float4 r0 = *(const float4*)&pw[k][m * 8];
                    const float4 r1 = *(const float4*)&pw[k][m * 8 + 4];
                    float a = s[m];
                    a = fmaf(r0.x, prev[0], a); a = fmaf(r0.y, prev[1], a);
                    a = fmaf(r0.z, prev[2], a); a = fmaf(r0.w, prev[3], a);
                    a = fmaf(r1.x, prev[4], a); a = fmaf(r1.y, prev[5], a);
                    a = fmaf(r1.z, prev[6], a); a = fmaf(r1.w, prev[7], a);
                    s[m] = a;
                }
            }
        }
        float* vj = &vs[js * VST + cs * NN];
        *(float4*)(vj)     = make_float4(s[0], s[1], s[2], s[3]);
        *(float4*)(vj + 4) = make_float4(s[4], s[5], s[6], s[7]);
    }
    __syncthreads();   // barrier 3: inclusive prefixes in vs

    // ---- phase 3: emit chunk j from incoming state (x from LDS, NT stores) ----
    float ci[NN];
    if (j > 0) {
        const float* vp = &vs[(j - 1) * VST + ch * NN];
        float4 p0 = *(const float4*)(vp);
        float4 p1 = *(const float4*)(vp + 4);
        ci[0] = p0.x; ci[1] = p0.y; ci[2] = p0.z; ci[3] = p0.w;
        ci[4] = p1.x; ci[5] = p1.y; ci[6] = p1.z; ci[7] = p1.w;
    } else {
#pragma unroll
        for (int m = 0; m < NN; ++m) ci[m] = 0.f;
    }

    float* op = out + (((size_t)b * SS + t0) * FF + f0 + ch) * NN;
#pragma unroll
    for (int i = 0; i < L; ++i) {
        const float xt = xs[xsidx(t0 + i, ch)];
        float cn[NN];
#pragma unroll
        for (int m = 0; m < NN; ++m) {
            float a = Bv[m] * xt;
#pragma unroll
            for (int n = 0; n < NN; ++n) a = fmaf(As[n * NN + m], ci[n], a);
            cn[m] = a;
        }
#pragma unroll
        for (int m = 0; m < NN; ++m) ci[m] = cn[m];

        f32x4* o4 = (f32x4*)(op + (size_t)i * (FF * NN));
        f32x4 lo = { ci[0], ci[1], ci[2], ci[3] };
        f32x4 hi = { ci[4], ci[5], ci[6], ci[7] };
        __builtin_nontemporal_store(lo, o4);
        __builtin_nontemporal_store(hi, o4 + 1);
    }
}

extern "C" void kernel_launch(void* const* d_in, const int* in_sizes, int n_in,
                              void* d_out, int out_size, void* d_ws, size_t ws_size,
                              hipStream_t stream) {
    const float* x  = (const float*)d_in[0];
    const float* Ad = (const float*)d_in[1];
    const float* Bd = (const float*)d_in[2];
    float* out = (float*)d_out;

    const int grid = BB * (FF / CGF);   // 1024 blocks
    hipLaunchKernelGGL(hippo_fused3, dim3(grid), dim3(NTF), 0, stream,
                       x, Ad, Bd, out);
}

// Round 11
// 36.351 us; speedup vs baseline: 1.8646x; 1.8646x over previous
//
#include <hip/hip_runtime.h>

#define BB 32
#define SS 512
#define FF 256
#define NN 8
#define L 16               // chunk length
#define NCH 32             // SS/L
#define CGF 8              // channels per block
#define NTF 256            // threads per block
#define XST 9              // xs base row stride (words)
#define VST 68             // vs row stride (words)

// chunk-skewed xs index: breaks the j-group 4-way bank conflict (-> <=2-way)
__device__ __forceinline__ int xsidx(int t, int c) {
    return t * XST + (t >> 4) + c;
}

__global__ __launch_bounds__(NTF) void hippo_fused4(
    const float* __restrict__ x,
    const float* __restrict__ Ad,
    const float* __restrict__ Bd,
    float* __restrict__ out)
{
    __shared__ __align__(16) float xs[SS * XST + NCH + 8];
    __shared__ __align__(16) float vs[NCH * VST];
    __shared__ __align__(16) float pw[5][64];         // P^(2^k), P = M^16
    __shared__ __align__(16) float Mp[4][64];         // M^1,2,4,8
    __shared__ __align__(16) float Ks[L][NN];         // K[i] = M^(15-i) B

    const int tid = threadIdx.x;

    // XCD-chunked swizzle
    const int h  = blockIdx.x;
    const int g  = (h & 7) * 128 + (h >> 3);
    const int b  = g >> 5;
    const int f0 = (g & 31) * CGF;

    // ---- wave 0: matrix algebra  ||  waves 1-3: stage x tile ----
    if (tid < 64) {
        const int m = tid >> 3, n = tid & 7;
        Mp[0][tid] = Ad[n * NN + m];                 // M = A^T
#pragma unroll
        for (int s = 1; s < 4; ++s) {                // M^2, M^4, M^8
            float a = 0.f;
#pragma unroll
            for (int t = 0; t < 8; ++t) a = fmaf(Mp[s-1][m*8+t], Mp[s-1][t*8+n], a);
            Mp[s][tid] = a;
        }
        {   float a = 0.f;                           // M^16
#pragma unroll
            for (int t = 0; t < 8; ++t) a = fmaf(Mp[3][m*8+t], Mp[3][t*8+n], a);
            pw[0][tid] = a; }
#pragma unroll
        for (int k = 1; k < 5; ++k) {                // M^32..M^256
            float a = 0.f;
#pragma unroll
            for (int t = 0; t < 8; ++t) a = fmaf(pw[k-1][m*8+t], pw[k-1][t*8+n], a);
            pw[k][tid] = a;
        }
        if (tid < L) {                               // K[i] = M^(15-i) B
            const int e = 15 - tid;
            float v[8];
#pragma unroll
            for (int q = 0; q < 8; ++q) v[q] = Bd[q];
#pragma unroll
            for (int s = 0; s < 4; ++s) {
                if (e & (1 << s)) {
                    float nv[8];
#pragma unroll
                    for (int r = 0; r < 8; ++r) {
                        float a = 0.f;
#pragma unroll
                        for (int c2 = 0; c2 < 8; ++c2)
                            a = fmaf(Mp[s][r * 8 + c2], v[c2], a);
                        nv[r] = a;
                    }
#pragma unroll
                    for (int r = 0; r < 8; ++r) v[r] = nv[r];
                }
            }
#pragma unroll
            for (int r = 0; r < 8; ++r) Ks[tid][r] = v[r];
        }
    } else {
        const float* xb = x + (size_t)b * SS * FF + f0;
#pragma unroll
        for (int k = 0; k < 6; ++k) {
            const int i2 = (tid - 64) + k * 192;     // 0..1151, need 0..1023
            if (i2 < 1024) {
                const int t = i2 >> 1, q = i2 & 1;
                float4 v = *(const float4*)(xb + (size_t)t * FF + q * 4);
                float* d = &xs[xsidx(t, q * 4)];
                d[0] = v.x; d[1] = v.y; d[2] = v.z; d[3] = v.w;
            }
        }
    }

    // thread-uniform A/B -> scalar regs (for emit)
    float As[NN * NN];
#pragma unroll
    for (int i = 0; i < NN * NN; ++i) As[i] = Ad[i];
    float Bv[NN];
#pragma unroll
    for (int m = 0; m < NN; ++m) Bv[m] = Bd[m];

    __syncthreads();   // barrier 1: xs + algebra ready

    // ---- phase 1: chunk-end state from zero via Krylov sum ----
    const int j  = tid >> 3;            // chunk 0..31
    const int ch = tid & 7;             // channel-in-block
    const int t0 = j * L;
    {
        float c[NN];
#pragma unroll
        for (int m = 0; m < NN; ++m) c[m] = 0.f;
#pragma unroll
        for (int i = 0; i < L; ++i) {
            const float xt = xs[xsidx(t0 + i, ch)];
            const float4 k0 = *(const float4*)&Ks[i][0];
            const float4 k1 = *(const float4*)&Ks[i][4];
            c[0] = fmaf(k0.x, xt, c[0]); c[1] = fmaf(k0.y, xt, c[1]);
            c[2] = fmaf(k0.z, xt, c[2]); c[3] = fmaf(k0.w, xt, c[3]);
            c[4] = fmaf(k1.x, xt, c[4]); c[5] = fmaf(k1.y, xt, c[5]);
            c[6] = fmaf(k1.z, xt, c[6]); c[7] = fmaf(k1.w, xt, c[7]);
        }
        float* vj = &vs[j * VST + ch * NN];
        *(float4*)(vj)     = make_float4(c[0], c[1], c[2], c[3]);
        *(float4*)(vj + 4) = make_float4(c[4], c[5], c[6], c[7]);
    }
    __syncthreads();   // barrier 2: chunk-end states in vs

    // ---- phase 2: in-wave shfl Hillis-Steele (no barriers) ----
    {
        const int lane = tid & 63;
        const int w    = tid >> 6;
        const int js   = lane >> 1;
        const int cs   = 2 * w + (lane & 1);

        float s[NN];
        {
            const float* vp = &vs[js * VST + cs * NN];
            float4 p0 = *(const float4*)(vp);
            float4 p1 = *(const float4*)(vp + 4);
            s[0] = p0.x; s[1] = p0.y; s[2] = p0.z; s[3] = p0.w;
            s[4] = p1.x; s[5] = p1.y; s[6] = p1.z; s[7] = p1.w;
        }
#pragma unroll
        for (int k = 0; k < 5; ++k) {
            const int d = 1 << k;
            float prev[NN];
#pragma unroll
            for (int m = 0; m < NN; ++m) prev[m] = __shfl_up(s[m], 2 * d, 64);
            if (js >= d) {
#pragma unroll
                for (int m = 0; m < NN; ++m) {
                    const float4 r0 = *(const float4*)&pw[k][m * 8];
                    const float4 r1 = *(const float4*)&pw[k][m * 8 + 4];
                    float a = s[m];
                    a = fmaf(r0.x, prev[0], a); a = fmaf(r0.y, prev[1], a);
                    a = fmaf(r0.z, prev[2], a); a = fmaf(r0.w, prev[3], a);
                    a = fmaf(r1.x, prev[4], a); a = fmaf(r1.y, prev[5], a);
                    a = fmaf(r1.z, prev[6], a); a = fmaf(r1.w, prev[7], a);
                    s[m] = a;
                }
            }
        }
        float* vj = &vs[js * VST + cs * NN];
        *(float4*)(vj)     = make_float4(s[0], s[1], s[2], s[3]);
        *(float4*)(vj + 4) = make_float4(s[4], s[5], s[6], s[7]);
    }
    __syncthreads();   // barrier 3: inclusive prefixes in vs

    // ---- phase 3: emit chunk j; 2-step batches, 4 back-to-back stores ----
    float ci[NN];
    if (j > 0) {
        const float* vp = &vs[(j - 1) * VST + ch * NN];
        float4 p0 = *(const float4*)(vp);
        float4 p1 = *(const float4*)(vp + 4);
        ci[0] = p0.x; ci[1] = p0.y; ci[2] = p0.z; ci[3] = p0.w;
        ci[4] = p1.x; ci[5] = p1.y; ci[6] = p1.z; ci[7] = p1.w;
    } else {
#pragma unroll
        for (int m = 0; m < NN; ++m) ci[m] = 0.f;
    }

    float* op = out + (((size_t)b * SS + t0) * FF + f0 + ch) * NN;
#pragma unroll
    for (int i0 = 0; i0 < L; i0 += 2) {
        float o0[NN], o1[NN];
        const float x0 = xs[xsidx(t0 + i0, ch)];
#pragma unroll
        for (int m = 0; m < NN; ++m) {
            float a = Bv[m] * x0;
#pragma unroll
            for (int n = 0; n < NN; ++n) a = fmaf(As[n * NN + m], ci[n], a);
            o0[m] = a;
        }
        const float x1 = xs[xsidx(t0 + i0 + 1, ch)];
#pragma unroll
        for (int m = 0; m < NN; ++m) {
            float a = Bv[m] * x1;
#pragma unroll
            for (int n = 0; n < NN; ++n) a = fmaf(As[n * NN + m], o0[n], a);
            o1[m] = a;
        }
#pragma unroll
        for (int m = 0; m < NN; ++m) ci[m] = o1[m];

        float4* p0 = (float4*)(op + (size_t)i0 * (FF * NN));
        float4* p1 = (float4*)(op + (size_t)(i0 + 1) * (FF * NN));
        p0[0] = make_float4(o0[0], o0[1], o0[2], o0[3]);
        p0[1] = make_float4(o0[4], o0[5], o0[6], o0[7]);
        p1[0] = make_float4(o1[0], o1[1], o1[2], o1[3]);
        p1[1] = make_float4(o1[4], o1[5], o1[6], o1[7]);
    }
}

extern "C" void kernel_launch(void* const* d_in, const int* in_sizes, int n_in,
                              void* d_out, int out_size, void* d_ws, size_t ws_size,
                              hipStream_t stream) {
    const float* x  = (const float*)d_in[0];
    const float* Ad = (const float*)d_in[1];
    const float* Bd = (const float*)d_in[2];
    float* out = (float*)d_out;

    const int grid = BB * (FF / CGF);   // 1024 blocks
    hipLaunchKernelGGL(hippo_fused4, dim3(grid), dim3(NTF), 0, stream,
                       x, Ad, Bd, out);
}